// Round 11
// baseline (186.392 us; speedup 1.0000x reference)
//
#include <hip/hip_runtime.h>
#include <hip/hip_bf16.h>
#include <cstdint>

typedef __attribute__((ext_vector_type(8))) short short8;
typedef __attribute__((ext_vector_type(4))) short short4v;
typedef __attribute__((ext_vector_type(4))) float floatx4;
typedef unsigned short ushort;

__device__ __forceinline__ float bf2f(ushort u) {
  unsigned int x = ((unsigned int)u) << 16;
  return __builtin_bit_cast(float, x);
}
__device__ __forceinline__ ushort f2bf(float f) {
  unsigned int x = __builtin_bit_cast(unsigned int, f);
  x += 0x7fffu + ((x >> 16) & 1u);   // RNE
  return (ushort)(x >> 16);
}

__device__ __forceinline__ void gload_lds16(const void* g, void* l) {
  __builtin_amdgcn_global_load_lds(
      (const __attribute__((address_space(1))) void*)g,
      (__attribute__((address_space(3))) void*)l, 16, 0, 0);
}

// ---------------- prep: x->bf16 (blocks 0..4095) + W transpose (4096..4863) ----------------

__global__ __launch_bounds__(256) void prep_kernel(const float* __restrict__ x,
                                                   const float* __restrict__ Wq,
                                                   const float* __restrict__ Wk,
                                                   const float* __restrict__ Wv,
                                                   ushort* __restrict__ xb,
                                                   ushort* __restrict__ Wt) {
  int bid = blockIdx.x;
  int tid = threadIdx.x;
  if (bid < 4096) {
    int i = bid * 256 + tid;
    const float4* xf = (const float4*)x;
    float4 a = xf[i * 2], b = xf[i * 2 + 1];
    short8 o;
    o[0] = (short)f2bf(a.x); o[1] = (short)f2bf(a.y);
    o[2] = (short)f2bf(a.z); o[3] = (short)f2bf(a.w);
    o[4] = (short)f2bf(b.x); o[5] = (short)f2bf(b.y);
    o[6] = (short)f2bf(b.z); o[7] = (short)f2bf(b.w);
    ((short8*)xb)[i] = o;
  } else {
    int t = bid - 4096;
    int z = t >> 8;
    int rem = t & 255;
    int c0 = (rem & 15) * 64;   // d_out block
    int r0 = (rem >> 4) * 64;   // d_in block
    const float* W = z == 0 ? Wq : (z == 1 ? Wk : Wv);
    ushort* O = Wt + (size_t)z * 1024 * 1024;
    __shared__ float tile[64][65];
#pragma unroll
    for (int i = 0; i < 4; ++i) {
      int c = tid + i * 256; int rr = c >> 4, q = c & 15;
      float4 v = *(const float4*)&W[(size_t)(r0 + rr) * 1024 + c0 + q * 4];
      tile[rr][q * 4 + 0] = v.x; tile[rr][q * 4 + 1] = v.y;
      tile[rr][q * 4 + 2] = v.z; tile[rr][q * 4 + 3] = v.w;
    }
    __syncthreads();
#pragma unroll
    for (int i = 0; i < 2; ++i) {
      int c = tid + i * 256; int oc = c >> 3, q = c & 7;
      short8 o;
#pragma unroll
      for (int j = 0; j < 8; ++j) o[j] = (short)f2bf(tile[q * 8 + j][oc]);
      *(short8*)&O[(size_t)(c0 + oc) * 1024 + r0 + q * 8] = o;
    }
  }
}

// ---------------- QKV: 256x384 tile, 8 waves, BK=32, triple-buffer, grid = 256 exact ----------------
// R8 structure with the occupancy-declaration fix: LDS (120 KiB) forces 1 block/CU,
// so declare min-waves-per-EU = 1 -> 256-VGPR budget; acc[8][6]=192 VGPR fits
// WITHOUT spilling (R8's spill was the (512,2) 128-VGPR cap, not the tile).

__global__ __launch_bounds__(512, 1) void qkv_kernel(const ushort* __restrict__ A,
                                                     const ushort* __restrict__ Bm,
                                                     ushort* __restrict__ Qo,
                                                     ushort* __restrict__ Ko,
                                                     ushort* __restrict__ Vt) {
  __shared__ __align__(16) ushort ldsA[3][8192];    // [buf][256*32] 48 KiB
  __shared__ __align__(16) ushort ldsB[3][12288];   // [buf][384*32] 72 KiB

  const int tid = threadIdx.x;
  const int lane = tid & 63;
  const int wave = tid >> 6;
  const int wm = wave >> 2;   // 0..1 -> 128-row half
  const int wn = wave & 3;    // 0..3 -> 96-col slice
  const int r15 = lane & 15;
  const int kg = lane >> 4;   // 0..3

  // XCD-bijective swizzle (nwg = 256, 256 % 8 == 0, chunk 32)
  int orig = blockIdx.y * 32 + blockIdx.x;
  int swz = (orig & 7) * 32 + (orig >> 3);
  const int m0 = (swz >> 3) * 256;   // 32 m-tiles
  const int n0 = (swz & 7) * 384;    // 8 n-tiles

  const ushort* Ag = A + (size_t)m0 * 1024;
  const ushort* Bg = Bm + (size_t)n0 * 1024;

  const int NKT = 32;  // 1024 / 32

  floatx4 acc[8][6] = {};

  auto stageA = [&](int kt) {
    ushort* dst = &ldsA[kt % 3][0];
    int k0 = kt * 32;
#pragma unroll
    for (int i = 0; i < 2; ++i) {
      int s = wave * 128 + i * 64 + lane;     // 1024 slots
      int d = s * 16;
      int L = d ^ (((d >> 7) & 3) << 4);
      gload_lds16(Ag + (size_t)(L >> 6) * 1024 + k0 + ((L & 63) >> 1), dst + s * 8);
    }
  };
  auto stageB = [&](int kt) {
    ushort* dst = &ldsB[kt % 3][0];
    int k0 = kt * 32;
#pragma unroll
    for (int i = 0; i < 3; ++i) {
      int s = wave * 192 + i * 64 + lane;     // 1536 slots
      int d = s * 16;
      int L = d ^ (((d >> 7) & 3) << 4);
      gload_lds16(Bg + (size_t)(L >> 6) * 1024 + k0 + ((L & 63) >> 1), dst + s * 8);
    }
  };

  auto ldA = [&](int buf, int m) -> short8 {
    int row = wm * 128 + m * 16 + r15;
    int P = (row * 64 + kg * 16) ^ (((row >> 1) & 3) << 4);
    return *(const short8*)((const char*)&ldsA[buf][0] + P);
  };
  auto ldB = [&](int buf, int n) -> short8 {
    int row = wn * 96 + n * 16 + r15;
    int P = (row * 64 + kg * 16) ^ (((row >> 1) & 3) << 4);
    return *(const short8*)((const char*)&ldsB[buf][0] + P);
  };

  // prologue: tiles 0 and 1 (10 loads/thread)
  stageA(0); stageB(0); stageA(1); stageB(1);
  asm volatile("s_waitcnt vmcnt(5)" ::: "memory");  // tile 0 landed
  __builtin_amdgcn_s_barrier();

  short8 bfrag[6], afrag[4];
  for (int kt = 0; kt < NKT; ++kt) {
    const int buf = kt % 3;

    // ---- phase0: B frags + A m0-3; stage A(kt+2) ----
#pragma unroll
    for (int n = 0; n < 6; ++n) bfrag[n] = ldB(buf, n);
#pragma unroll
    for (int m = 0; m < 4; ++m) afrag[m] = ldA(buf, m);
    if (kt + 2 < NKT) stageA(kt + 2);
    __builtin_amdgcn_s_barrier();
    asm volatile("s_waitcnt lgkmcnt(0)" ::: "memory");
    __builtin_amdgcn_sched_barrier(0);
    __builtin_amdgcn_s_setprio(1);
#pragma unroll
    for (int m = 0; m < 4; ++m)
#pragma unroll
      for (int n = 0; n < 6; ++n)
        acc[m][n] = __builtin_amdgcn_mfma_f32_16x16x32_bf16(afrag[m], bfrag[n], acc[m][n], 0, 0, 0);
    __builtin_amdgcn_s_setprio(0);
    __builtin_amdgcn_s_barrier();

    // ---- phase1: A m4-7; stage B(kt+2); counted wait gating next buf ----
#pragma unroll
    for (int m = 0; m < 4; ++m) afrag[m] = ldA(buf, m + 4);
    if (kt + 2 < NKT) stageB(kt + 2);
    if (kt < NKT - 2)
      asm volatile("s_waitcnt vmcnt(5)" ::: "memory");   // tile kt+1 landed
    else if (kt == NKT - 2)
      asm volatile("s_waitcnt vmcnt(0)" ::: "memory");   // tail drain
    __builtin_amdgcn_s_barrier();
    asm volatile("s_waitcnt lgkmcnt(0)" ::: "memory");
    __builtin_amdgcn_sched_barrier(0);
    __builtin_amdgcn_s_setprio(1);
#pragma unroll
    for (int m = 0; m < 4; ++m)
#pragma unroll
      for (int n = 0; n < 6; ++n)
        acc[m + 4][n] = __builtin_amdgcn_mfma_f32_16x16x32_bf16(afrag[m], bfrag[n], acc[m + 4][n], 0, 0, 0);
    __builtin_amdgcn_s_setprio(0);
    __builtin_amdgcn_s_barrier();
  }

  // ---- epilogue: per-frag z select (frags 16-wide; 1024-boundaries 16-aligned) ----
  const int rq = kg * 4;
#pragma unroll
  for (int m = 0; m < 8; ++m) {
    int grb = m0 + wm * 128 + m * 16 + rq;   // 4-aligned output row
#pragma unroll
    for (int n = 0; n < 6; ++n) {
      int gc0 = n0 + wn * 96 + n * 16;
      if (gc0 < 2048) {
        ushort* Cz = gc0 < 1024 ? Qo : Ko;
        int col = (gc0 & 1023) + r15;
#pragma unroll
        for (int r = 0; r < 4; ++r)
          Cz[(size_t)(grb + r) * 1024 + col] = f2bf(acc[m][n][r]);
      } else {
        // V: store transposed -> Vt[b][e][t], 4 consecutive t per lane = 8B store
        int e = gc0 - 2048 + r15;
        int b = grb >> 11;
        int t = grb & 2047;
        short4v o;
#pragma unroll
        for (int r = 0; r < 4; ++r) o[r] = (short)f2bf(acc[m][n][r]);
        *(short4v*)&Vt[((size_t)b * 1024 + e) * 2048 + t] = o;
      }
    }
  }
}

// ---------------- S: TN GEMM + fused exp + per-block row sums (frozen at R9) ----------------

__global__ __launch_bounds__(256) void s_kernel(const ushort* __restrict__ Q,
                                                const ushort* __restrict__ K,
                                                ushort* __restrict__ S,
                                                float* __restrict__ Lpart) {
  int t = blockIdx.x;
  int qb = (int)((sqrtf(8.f * (float)t + 1.f) - 1.f) * 0.5f);
  while ((qb + 1) * (qb + 2) / 2 <= t) ++qb;
  while (qb * (qb + 1) / 2 > t) --qb;
  int kb = t - qb * (qb + 1) / 2;
  const size_t bi = blockIdx.y;
  const ushort* Ag = Q + bi * 2048 * 1024 + (size_t)qb * 128 * 1024;
  const ushort* Bg = K + bi * 2048 * 1024 + (size_t)kb * 128 * 1024;
  ushort* C = S + bi * 2048 * 2048;
  const int m0 = qb * 128, n0 = kb * 128;

  __shared__ __align__(16) ushort Asm[2][128 * 32];
  __shared__ __align__(16) ushort Bsm[2][128 * 32];
  __shared__ float rsum_lds[4][64];
  const int tid = threadIdx.x;
  const int lane = tid & 63;
  const int wave = tid >> 6;
  const int wrow = (wave >> 1) * 64;
  const int wcol = (wave & 1) * 64;
  const int r15 = lane & 15;
  const int kg = (lane >> 4) * 8;

  floatx4 acc[4][4] = {};

  auto stage = [&](int buf, int kt) {
    int k0 = kt * 32;
#pragma unroll
    for (int i = 0; i < 2; ++i) {
      int c = tid + i * 256;
      gload_lds16(Ag + (size_t)(c >> 2) * 1024 + k0 + (c & 3) * 8, &Asm[buf][c * 8]);
    }
#pragma unroll
    for (int i = 0; i < 2; ++i) {
      int c = tid + i * 256;
      gload_lds16(Bg + (size_t)(c >> 2) * 1024 + k0 + (c & 3) * 8, &Bsm[buf][c * 8]);
    }
  };

  stage(0, 0);
  for (int kt = 0; kt < 32; ++kt) {
    int cur = kt & 1;
    __syncthreads();
    if (kt + 1 < 32) stage(cur ^ 1, kt + 1);
    short8 af[4], bfr[4];
#pragma unroll
    for (int m = 0; m < 4; ++m)
      af[m] = *(const short8*)&Asm[cur][(wrow + m * 16 + r15) * 32 + kg];
#pragma unroll
    for (int n = 0; n < 4; ++n)
      bfr[n] = *(const short8*)&Bsm[cur][(wcol + n * 16 + r15) * 32 + kg];
#pragma unroll
    for (int m = 0; m < 4; ++m)
#pragma unroll
      for (int n = 0; n < 4; ++n)
        acc[m][n] = __builtin_amdgcn_mfma_f32_16x16x32_bf16(af[m], bfr[n], acc[m][n], 0, 0, 0);
  }

  const int rq = (lane >> 4) * 4;
  const float K2 = 0.03125f * 1.44269504f;   // scale * log2(e)
#pragma unroll
  for (int m = 0; m < 4; ++m) {
    float rs[4] = {0.f, 0.f, 0.f, 0.f};
#pragma unroll
    for (int n = 0; n < 4; ++n) {
      int gc = n0 + wcol + n * 16 + r15;
#pragma unroll
      for (int r = 0; r < 4; ++r) {
        int gr = m0 + wrow + m * 16 + rq + r;
        float ev = (gc <= gr) ? __builtin_amdgcn_exp2f(acc[m][n][r] * K2) : 0.f;
        C[(size_t)gr * 2048 + gc] = f2bf(ev);
        rs[r] += ev;
      }
    }
#pragma unroll
    for (int r = 0; r < 4; ++r) {
#pragma unroll
      for (int off = 1; off < 16; off <<= 1) rs[r] += __shfl_xor(rs[r], off, 64);
    }
    if (r15 == 0) {
#pragma unroll
      for (int r = 0; r < 4; ++r) rsum_lds[wave][m * 16 + rq + r] = rs[r];
    }
  }
  __syncthreads();
  if (tid < 128) {
    int h = tid >> 6;
    int lr = tid & 63;
    float v = rsum_lds[h * 2][lr] + rsum_lds[h * 2 + 1][lr];
    Lpart[((size_t)bi * 16 + kb) * 2048 + m0 + h * 64 + lr] = v;
  }
}

// ---------------- PV: O = (E @ V) * (1/sum), lred fused, heavy-first (frozen at R9) ----------------

__global__ __launch_bounds__(256) void pv_kernel(const ushort* __restrict__ E,
                                                 const ushort* __restrict__ Vt,
                                                 const float* __restrict__ Lpart,
                                                 float* __restrict__ O) {
  const int qb = 15 - blockIdx.x;
  const int nb = blockIdx.y;
  const size_t bi = blockIdx.z;
  const int kTiles = (qb + 1) * 4;
  const ushort* Ag = E + bi * 2048 * 2048 + (size_t)qb * 128 * 2048;
  const ushort* Bg = Vt + bi * 1024 * 2048 + (size_t)nb * 128 * 2048;
  float* Ob = O + bi * 2048 * 1024;
  const int m0 = qb * 128, n0 = nb * 128;

  __shared__ __align__(16) ushort Asm[2][128 * 32];
  __shared__ __align__(16) ushort Bsm[2][128 * 32];
  __shared__ float ilp[128];
  const int tid = threadIdx.x;
  const int lane = tid & 63;
  const int wave = tid >> 6;
  const int wrow = (wave >> 1) * 64;
  const int wcol = (wave & 1) * 64;
  const int r15 = lane & 15;
  const int kg = (lane >> 4) * 8;

  floatx4 acc[4][4] = {};

  // fused lred: 1 / sum_kb Lpart for this block's 128 rows
  if (tid < 128) {
    float ssum = 0.f;
    for (int kb = 0; kb <= qb; ++kb)
      ssum += Lpart[((size_t)bi * 16 + kb) * 2048 + m0 + tid];
    ilp[tid] = 1.f / ssum;
  }

  auto stage = [&](int buf, int kt) {
    int k0 = kt * 32;
#pragma unroll
    for (int i = 0; i < 2; ++i) {
      int c = tid + i * 256;
      gload_lds16(Ag + (size_t)(c >> 2) * 2048 + k0 + (c & 3) * 8, &Asm[buf][c * 8]);
    }
#pragma unroll
    for (int i = 0; i < 2; ++i) {
      int c = tid + i * 256;
      gload_lds16(Bg + (size_t)(c >> 2) * 2048 + k0 + (c & 3) * 8, &Bsm[buf][c * 8]);
    }
  };

  stage(0, 0);
  for (int kt = 0; kt < kTiles; ++kt) {
    int cur = kt & 1;
    __syncthreads();
    if (kt + 1 < kTiles) stage(cur ^ 1, kt + 1);
    short8 af[4], bfr[4];
#pragma unroll
    for (int m = 0; m < 4; ++m)
      af[m] = *(const short8*)&Asm[cur][(wrow + m * 16 + r15) * 32 + kg];
#pragma unroll
    for (int n = 0; n < 4; ++n)
      bfr[n] = *(const short8*)&Bsm[cur][(wcol + n * 16 + r15) * 32 + kg];
#pragma unroll
    for (int m = 0; m < 4; ++m)
#pragma unroll
      for (int n = 0; n < 4; ++n)
        acc[m][n] = __builtin_amdgcn_mfma_f32_16x16x32_bf16(af[m], bfr[n], acc[m][n], 0, 0, 0);
  }

  const int rq = (lane >> 4) * 4;
#pragma unroll
  for (int m = 0; m < 4; ++m) {
#pragma unroll
    for (int r = 0; r < 4; ++r) {
      int lr = wrow + m * 16 + rq + r;
      float il = ilp[lr];
      int gr = m0 + lr;
#pragma unroll
      for (int n = 0; n < 4; ++n) {
        int gc = n0 + wcol + n * 16 + r15;
        Ob[(size_t)gr * 1024 + gc] = acc[m][n][r] * il;
      }
    }
  }
}

// ---------------- launch ----------------

extern "C" void kernel_launch(void* const* d_in, const int* in_sizes, int n_in,
                              void* d_out, int out_size, void* d_ws, size_t ws_size,
                              hipStream_t stream) {
  const float* x  = (const float*)d_in[0];
  const float* Wq = (const float*)d_in[1];
  const float* Wk = (const float*)d_in[2];
  const float* Wv = (const float*)d_in[3];
  float* out = (float*)d_out;

  ushort* Xb  = (ushort*)d_ws;                        // 8192*1024
  ushort* Wt  = Xb + (size_t)8192 * 1024;             // 3*1024*1024
  ushort* QK  = Wt + (size_t)3 * 1024 * 1024;         // 2*8192*1024 (Q then K)
  ushort* Vt  = QK + (size_t)2 * 8192 * 1024;         // 4*1024*2048
  ushort* S   = Vt + (size_t)4 * 1024 * 2048;         // 4*2048*2048 (E values)
  float*  Lpart = (float*)(S + (size_t)4 * 2048 * 2048);  // 4*16*2048 f32

  ushort* Qp = QK;
  ushort* Kp = QK + (size_t)8192 * 1024;

  hipLaunchKernelGGL(prep_kernel, dim3(4864), dim3(256), 0, stream, x, Wq, Wk, Wv, Xb, Wt);
  hipLaunchKernelGGL(qkv_kernel, dim3(32, 8), dim3(512), 0, stream, Xb, Wt, Qp, Kp, Vt);
  hipLaunchKernelGGL(s_kernel, dim3(136, 4), dim3(256), 0, stream, Qp, Kp, S, Lpart);
  hipLaunchKernelGGL(pv_kernel, dim3(16, 8, 4), dim3(256), 0, stream, S, Vt, Lpart, out);
}

// Round 12
// 174.487 us; speedup vs baseline: 1.0682x; 1.0682x over previous
//
#include <hip/hip_runtime.h>
#include <hip/hip_bf16.h>
#include <cstdint>

typedef __attribute__((ext_vector_type(8))) short short8;
typedef __attribute__((ext_vector_type(4))) short short4v;
typedef __attribute__((ext_vector_type(4))) float floatx4;
typedef unsigned short ushort;

__device__ __forceinline__ float bf2f(ushort u) {
  unsigned int x = ((unsigned int)u) << 16;
  return __builtin_bit_cast(float, x);
}
__device__ __forceinline__ ushort f2bf(float f) {
  unsigned int x = __builtin_bit_cast(unsigned int, f);
  x += 0x7fffu + ((x >> 16) & 1u);   // RNE
  return (ushort)(x >> 16);
}

__device__ __forceinline__ void gload_lds16(const void* g, void* l) {
  __builtin_amdgcn_global_load_lds(
      (const __attribute__((address_space(1))) void*)g,
      (__attribute__((address_space(3))) void*)l, 16, 0, 0);
}

// ---------------- prep: x->bf16 (blocks 0..4095) + W transpose (4096..4863) ----------------

__global__ __launch_bounds__(256) void prep_kernel(const float* __restrict__ x,
                                                   const float* __restrict__ Wq,
                                                   const float* __restrict__ Wk,
                                                   const float* __restrict__ Wv,
                                                   ushort* __restrict__ xb,
                                                   ushort* __restrict__ Wt) {
  int bid = blockIdx.x;
  int tid = threadIdx.x;
  if (bid < 4096) {
    int i = bid * 256 + tid;
    const float4* xf = (const float4*)x;
    float4 a = xf[i * 2], b = xf[i * 2 + 1];
    short8 o;
    o[0] = (short)f2bf(a.x); o[1] = (short)f2bf(a.y);
    o[2] = (short)f2bf(a.z); o[3] = (short)f2bf(a.w);
    o[4] = (short)f2bf(b.x); o[5] = (short)f2bf(b.y);
    o[6] = (short)f2bf(b.z); o[7] = (short)f2bf(b.w);
    ((short8*)xb)[i] = o;
  } else {
    int t = bid - 4096;
    int z = t >> 8;
    int rem = t & 255;
    int c0 = (rem & 15) * 64;   // d_out block
    int r0 = (rem >> 4) * 64;   // d_in block
    const float* W = z == 0 ? Wq : (z == 1 ? Wk : Wv);
    ushort* O = Wt + (size_t)z * 1024 * 1024;
    __shared__ float tile[64][65];
#pragma unroll
    for (int i = 0; i < 4; ++i) {
      int c = tid + i * 256; int rr = c >> 4, q = c & 15;
      float4 v = *(const float4*)&W[(size_t)(r0 + rr) * 1024 + c0 + q * 4];
      tile[rr][q * 4 + 0] = v.x; tile[rr][q * 4 + 1] = v.y;
      tile[rr][q * 4 + 2] = v.z; tile[rr][q * 4 + 3] = v.w;
    }
    __syncthreads();
#pragma unroll
    for (int i = 0; i < 2; ++i) {
      int c = tid + i * 256; int oc = c >> 3, q = c & 7;
      short8 o;
#pragma unroll
      for (int j = 0; j < 8; ++j) o[j] = (short)f2bf(tile[q * 8 + j][oc]);
      *(short8*)&O[(size_t)(c0 + oc) * 1024 + r0 + q * 8] = o;
    }
  }
}

// ---------------- QKV: 256x256, 8 waves, BK=64, R2 schedule (best measured, R9) ----------------

__global__ __launch_bounds__(512, 2) void qkv8_kernel(const ushort* __restrict__ A,
                                                      const ushort* __restrict__ Bm,
                                                      ushort* __restrict__ Qo,
                                                      ushort* __restrict__ Ko,
                                                      ushort* __restrict__ Vt) {
  __shared__ __align__(16) ushort lds[2][2][2][8192];

  const int tid = threadIdx.x;
  const int lane = tid & 63;
  const int wave = tid >> 6;
  const int wm = wave >> 2;
  const int wn = wave & 3;
  const int r15 = lane & 15;
  const int kg = lane >> 4;

  const int nwgx = 32, nwgy = 12;
  int orig = blockIdx.y * nwgx + blockIdx.x;
  int swz = (orig & 7) * ((nwgx * nwgy) >> 3) + (orig >> 3);
  int by = swz % nwgy;
  int bx = swz / nwgy;
  const int m0 = bx * 256;
  const int n0 = by * 256;

  const ushort* Ag = A + (size_t)m0 * 1024;
  const ushort* Bg = Bm + (size_t)n0 * 1024;

  const int NKT = 16;

  floatx4 acc[8][4] = {};

  auto stage = [&](int sidx) {
    int kt = sidx >> 2, hh = sidx & 3;
    int mat = hh & 1, kh = hh >> 1;
    ushort* dst = &lds[kt & 1][mat][kh][0];
    const ushort* src = mat ? Bg : Ag;
    int kbase = kt * 64 + kh * 32;
#pragma unroll
    for (int i = 0; i < 2; ++i) {
      int t = tid + i * 512;
      int d = t * 16;
      int L = d ^ (((d >> 7) & 3) << 4);
      int row = L >> 6;
      int colE = (L & 63) >> 1;
      gload_lds16(src + (size_t)row * 1024 + kbase + colE, dst + t * 8);
    }
  };

  auto ldA = [&](int buf, int ks, int m) -> short8 {
    int row = wm * 128 + m * 16 + r15;
    int L = row * 64 + kg * 16;
    int P = L ^ (((row >> 1) & 3) << 4);
    return *(const short8*)((const char*)&lds[buf][0][ks][0] + P);
  };
  auto ldB = [&](int buf, int ks, int n) -> short8 {
    int row = wn * 64 + n * 16 + r15;
    int L = row * 64 + kg * 16;
    int P = L ^ (((row >> 1) & 3) << 4);
    return *(const short8*)((const char*)&lds[buf][1][ks][0] + P);
  };

  for (int s = 0; s < 6; ++s) stage(s);
  asm volatile("s_waitcnt vmcnt(8)" ::: "memory");
  __builtin_amdgcn_s_barrier();

  short8 bfrag[4];
  int sidx = 6;
  for (int kt = 0; kt < NKT; ++kt) {
    int cur = kt & 1;
#pragma unroll
    for (int q = 0; q < 4; ++q) {
      const int ks = q >> 1;
      const int msub = (q & 1) * 4;
      short8 afrag[4];
      if ((q & 1) == 0) {
#pragma unroll
        for (int n = 0; n < 4; ++n) bfrag[n] = ldB(cur, ks, n);
      }
#pragma unroll
      for (int m = 0; m < 4; ++m) afrag[m] = ldA(cur, ks, msub + m);
      if (sidx < NKT * 4) stage(sidx);
      ++sidx;
      if (q & 1) asm volatile("s_waitcnt vmcnt(4)" ::: "memory");
      __builtin_amdgcn_s_barrier();
      __builtin_amdgcn_s_setprio(1);
#pragma unroll
      for (int m = 0; m < 4; ++m)
#pragma unroll
        for (int n = 0; n < 4; ++n)
          acc[msub + m][n] =
              __builtin_amdgcn_mfma_f32_16x16x32_bf16(afrag[m], bfrag[n], acc[msub + m][n], 0, 0, 0);
      __builtin_amdgcn_s_setprio(0);
      __builtin_amdgcn_s_barrier();
    }
  }

  const int z = n0 >> 10;
  const int rq = kg * 4;
  if (z < 2) {
    ushort* Cz = z == 0 ? Qo : Ko;
    const int cb = n0 & 1023;
#pragma unroll
    for (int m = 0; m < 8; ++m) {
#pragma unroll
      for (int n = 0; n < 4; ++n) {
        int gc = cb + wn * 64 + n * 16 + r15;
#pragma unroll
        for (int r = 0; r < 4; ++r) {
          int gr = m0 + wm * 128 + m * 16 + rq + r;
          Cz[(size_t)gr * 1024 + gc] = f2bf(acc[m][n][r]);
        }
      }
    }
  } else {
#pragma unroll
    for (int m = 0; m < 8; ++m) {
      int gr = m0 + wm * 128 + m * 16 + rq;
      int b = gr >> 11;
      int t = gr & 2047;
      ushort* Vb = Vt + (size_t)b * 1024 * 2048;
#pragma unroll
      for (int n = 0; n < 4; ++n) {
        int e = (n0 - 2048) + wn * 64 + n * 16 + r15;
        short4v o;
#pragma unroll
        for (int r = 0; r < 4; ++r) o[r] = (short)f2bf(acc[m][n][r]);
        *(short4v*)&Vb[(size_t)e * 2048 + t] = o;
      }
    }
  }
}

// ---------------- S: TN GEMM + fused exp + per-block row sums (R9) ----------------

__global__ __launch_bounds__(256) void s_kernel(const ushort* __restrict__ Q,
                                                const ushort* __restrict__ K,
                                                ushort* __restrict__ S,
                                                float* __restrict__ Lpart) {
  int t = blockIdx.x;
  int qb = (int)((sqrtf(8.f * (float)t + 1.f) - 1.f) * 0.5f);
  while ((qb + 1) * (qb + 2) / 2 <= t) ++qb;
  while (qb * (qb + 1) / 2 > t) --qb;
  int kb = t - qb * (qb + 1) / 2;
  const size_t bi = blockIdx.y;
  const ushort* Ag = Q + bi * 2048 * 1024 + (size_t)qb * 128 * 1024;
  const ushort* Bg = K + bi * 2048 * 1024 + (size_t)kb * 128 * 1024;
  ushort* C = S + bi * 2048 * 2048;
  const int m0 = qb * 128, n0 = kb * 128;

  __shared__ __align__(16) ushort Asm[2][128 * 32];
  __shared__ __align__(16) ushort Bsm[2][128 * 32];
  __shared__ float rsum_lds[4][64];
  const int tid = threadIdx.x;
  const int lane = tid & 63;
  const int wave = tid >> 6;
  const int wrow = (wave >> 1) * 64;
  const int wcol = (wave & 1) * 64;
  const int r15 = lane & 15;
  const int kg = (lane >> 4) * 8;

  floatx4 acc[4][4] = {};

  auto stage = [&](int buf, int kt) {
    int k0 = kt * 32;
#pragma unroll
    for (int i = 0; i < 2; ++i) {
      int c = tid + i * 256;
      gload_lds16(Ag + (size_t)(c >> 2) * 1024 + k0 + (c & 3) * 8, &Asm[buf][c * 8]);
    }
#pragma unroll
    for (int i = 0; i < 2; ++i) {
      int c = tid + i * 256;
      gload_lds16(Bg + (size_t)(c >> 2) * 1024 + k0 + (c & 3) * 8, &Bsm[buf][c * 8]);
    }
  };

  stage(0, 0);
  for (int kt = 0; kt < 32; ++kt) {
    int cur = kt & 1;
    __syncthreads();
    if (kt + 1 < 32) stage(cur ^ 1, kt + 1);
    short8 af[4], bfr[4];
#pragma unroll
    for (int m = 0; m < 4; ++m)
      af[m] = *(const short8*)&Asm[cur][(wrow + m * 16 + r15) * 32 + kg];
#pragma unroll
    for (int n = 0; n < 4; ++n)
      bfr[n] = *(const short8*)&Bsm[cur][(wcol + n * 16 + r15) * 32 + kg];
#pragma unroll
    for (int m = 0; m < 4; ++m)
#pragma unroll
      for (int n = 0; n < 4; ++n)
        acc[m][n] = __builtin_amdgcn_mfma_f32_16x16x32_bf16(af[m], bfr[n], acc[m][n], 0, 0, 0);
  }

  const int rq = (lane >> 4) * 4;
  const float K2 = 0.03125f * 1.44269504f;   // scale * log2(e)
#pragma unroll
  for (int m = 0; m < 4; ++m) {
    float rs[4] = {0.f, 0.f, 0.f, 0.f};
#pragma unroll
    for (int n = 0; n < 4; ++n) {
      int gc = n0 + wcol + n * 16 + r15;
#pragma unroll
      for (int r = 0; r < 4; ++r) {
        int gr = m0 + wrow + m * 16 + rq + r;
        float ev = (gc <= gr) ? __builtin_amdgcn_exp2f(acc[m][n][r] * K2) : 0.f;
        C[(size_t)gr * 2048 + gc] = f2bf(ev);
        rs[r] += ev;
      }
    }
#pragma unroll
    for (int r = 0; r < 4; ++r) {
#pragma unroll
      for (int off = 1; off < 16; off <<= 1) rs[r] += __shfl_xor(rs[r], off, 64);
    }
    if (r15 == 0) {
#pragma unroll
      for (int r = 0; r < 4; ++r) rsum_lds[wave][m * 16 + rq + r] = rs[r];
    }
  }
  __syncthreads();
  if (tid < 128) {
    int h = tid >> 6;
    int lr = tid & 63;
    float v = rsum_lds[h * 2][lr] + rsum_lds[h * 2 + 1][lr];
    Lpart[((size_t)bi * 16 + kb) * 2048 + m0 + h * 64 + lr] = v;
  }
}

// ---------------- PV: O = (E @ V) * (1/sum), lred fused, heavy-first (R9) ----------------

__global__ __launch_bounds__(256) void pv_kernel(const ushort* __restrict__ E,
                                                 const ushort* __restrict__ Vt,
                                                 const float* __restrict__ Lpart,
                                                 float* __restrict__ O) {
  const int qb = 15 - blockIdx.x;
  const int nb = blockIdx.y;
  const size_t bi = blockIdx.z;
  const int kTiles = (qb + 1) * 4;
  const ushort* Ag = E + bi * 2048 * 2048 + (size_t)qb * 128 * 2048;
  const ushort* Bg = Vt + bi * 1024 * 2048 + (size_t)nb * 128 * 2048;
  float* Ob = O + bi * 2048 * 1024;
  const int m0 = qb * 128, n0 = nb * 128;

  __shared__ __align__(16) ushort Asm[2][128 * 32];
  __shared__ __align__(16) ushort Bsm[2][128 * 32];
  __shared__ float ilp[128];
  const int tid = threadIdx.x;
  const int lane = tid & 63;
  const int wave = tid >> 6;
  const int wrow = (wave >> 1) * 64;
  const int wcol = (wave & 1) * 64;
  const int r15 = lane & 15;
  const int kg = (lane >> 4) * 8;

  floatx4 acc[4][4] = {};

  // fused lred: 1 / sum_kb Lpart for this block's 128 rows
  if (tid < 128) {
    float ssum = 0.f;
    for (int kb = 0; kb <= qb; ++kb)
      ssum += Lpart[((size_t)bi * 16 + kb) * 2048 + m0 + tid];
    ilp[tid] = 1.f / ssum;
  }

  auto stage = [&](int buf, int kt) {
    int k0 = kt * 32;
#pragma unroll
    for (int i = 0; i < 2; ++i) {
      int c = tid + i * 256;
      gload_lds16(Ag + (size_t)(c >> 2) * 2048 + k0 + (c & 3) * 8, &Asm[buf][c * 8]);
    }
#pragma unroll
    for (int i = 0; i < 2; ++i) {
      int c = tid + i * 256;
      gload_lds16(Bg + (size_t)(c >> 2) * 2048 + k0 + (c & 3) * 8, &Bsm[buf][c * 8]);
    }
  };

  stage(0, 0);
  for (int kt = 0; kt < kTiles; ++kt) {
    int cur = kt & 1;
    __syncthreads();
    if (kt + 1 < kTiles) stage(cur ^ 1, kt + 1);
    short8 af[4], bfr[4];
#pragma unroll
    for (int m = 0; m < 4; ++m)
      af[m] = *(const short8*)&Asm[cur][(wrow + m * 16 + r15) * 32 + kg];
#pragma unroll
    for (int n = 0; n < 4; ++n)
      bfr[n] = *(const short8*)&Bsm[cur][(wcol + n * 16 + r15) * 32 + kg];
#pragma unroll
    for (int m = 0; m < 4; ++m)
#pragma unroll
      for (int n = 0; n < 4; ++n)
        acc[m][n] = __builtin_amdgcn_mfma_f32_16x16x32_bf16(af[m], bfr[n], acc[m][n], 0, 0, 0);
  }

  const int rq = (lane >> 4) * 4;
#pragma unroll
  for (int m = 0; m < 4; ++m) {
#pragma unroll
    for (int r = 0; r < 4; ++r) {
      int lr = wrow + m * 16 + rq + r;
      float il = ilp[lr];
      int gr = m0 + lr;
#pragma unroll
      for (int n = 0; n < 4; ++n) {
        int gc = n0 + wcol + n * 16 + r15;
        Ob[(size_t)gr * 1024 + gc] = acc[m][n][r] * il;
      }
    }
  }
}

// ---------------- launch ----------------

extern "C" void kernel_launch(void* const* d_in, const int* in_sizes, int n_in,
                              void* d_out, int out_size, void* d_ws, size_t ws_size,
                              hipStream_t stream) {
  const float* x  = (const float*)d_in[0];
  const float* Wq = (const float*)d_in[1];
  const float* Wk = (const float*)d_in[2];
  const float* Wv = (const float*)d_in[3];
  float* out = (float*)d_out;

  ushort* Xb  = (ushort*)d_ws;                        // 8192*1024
  ushort* Wt  = Xb + (size_t)8192 * 1024;             // 3*1024*1024
  ushort* QK  = Wt + (size_t)3 * 1024 * 1024;         // 2*8192*1024 (Q then K)
  ushort* Vt  = QK + (size_t)2 * 8192 * 1024;         // 4*1024*2048
  ushort* S   = Vt + (size_t)4 * 1024 * 2048;         // 4*2048*2048 (E values)
  float*  Lpart = (float*)(S + (size_t)4 * 2048 * 2048);  // 4*16*2048 f32

  ushort* Qp = QK;
  ushort* Kp = QK + (size_t)8192 * 1024;

  hipLaunchKernelGGL(prep_kernel, dim3(4864), dim3(256), 0, stream, x, Wq, Wk, Wv, Xb, Wt);
  hipLaunchKernelGGL(qkv8_kernel, dim3(32, 12), dim3(512), 0, stream, Xb, Wt, Qp, Kp, Vt);
  hipLaunchKernelGGL(s_kernel, dim3(136, 4), dim3(256), 0, stream, Qp, Kp, S, Lpart);
  hipLaunchKernelGGL(pv_kernel, dim3(16, 8, 4), dim3(256), 0, stream, S, Vt, Lpart, out);
}